// Round 1
// baseline (322.665 us; speedup 1.0000x reference)
//
#include <hip/hip_runtime.h>
#include <stdint.h>

typedef unsigned short u16;
typedef short bf16x8 __attribute__((ext_vector_type(8)));
typedef short bf16x4 __attribute__((ext_vector_type(4)));
typedef float f32x4 __attribute__((ext_vector_type(4)));

#define NN 384
#define DIMC 128
#define NPOS (NN*NN)
#define EPSV 1e-5f

__device__ __forceinline__ u16 f2b(float f){
  union { float f; uint32_t u; } v; v.f = f;
  return (u16)((v.u + 0x7FFFu + ((v.u >> 16) & 1u)) >> 16);
}
__device__ __forceinline__ float b2f(u16 h){
  union { uint32_t u; float f; } v; v.u = ((uint32_t)h) << 16;
  return v.f;
}
__device__ __forceinline__ float sigm(float z){ return 1.0f/(1.0f + __expf(-z)); }

// ---------------- kernel 0: fp32 -> bf16 weight conversion ----------------
// dst layout: [0]=left_w [1]=lgate_w [2]=right_w [3]=rgate_w [4]=ogate_w [5]=out_w
__global__ void wconv_k(const float* __restrict__ s0, const float* __restrict__ s1,
                        const float* __restrict__ s2, const float* __restrict__ s3,
                        const float* __restrict__ s4, const float* __restrict__ s5,
                        u16* __restrict__ dst){
  int bid = blockIdx.x;
  int m = bid >> 6;                       // 64 blocks per 16384-elem matrix
  int off = ((bid & 63) << 8) + threadIdx.x;
  const float* src = s0;
  if (m==1) src=s1; else if (m==2) src=s2; else if (m==3) src=s3;
  else if (m==4) src=s4; else if (m==5) src=s5;
  dst[(m<<14) + off] = f2b(src[off]);
}

// ---------------- kernel 1: LN + 5 projections (fused) ----------------
// block: fixed column c, 64 consecutive rows r0..r0+63. 256 threads (4 waves).
// outputs: Lp[d][j=c][k=r], Rp[d][i=c][k=r] (bf16, k-contiguous), gate[i][j][e] (bf16, post-sigmoid)
__global__ __launch_bounds__(256) void phase1_k(
    const float* __restrict__ x, const float* __restrict__ nw, const float* __restrict__ nb,
    const u16* __restrict__ wb,
    const float* __restrict__ left_b, const float* __restrict__ lgate_b,
    const float* __restrict__ right_b, const float* __restrict__ rgate_b,
    const float* __restrict__ ogate_b,
    u16* __restrict__ Lp, u16* __restrict__ Rp, u16* __restrict__ gate)
{
  __shared__ u16 xn[64*136];   // [pos][128+8 pad] bf16
  __shared__ u16 trans[8704];  // reused staging: [e][64+4] or [pos][128+4]
  const int tid = threadIdx.x, lane = tid & 63, wid = tid >> 6;
  const int bid = blockIdx.x;
  const int c = bid % NN, r0 = (bid / NN) * 64;

  float2 nw2 = *(const float2*)(nw + 2*lane);
  float2 nb2 = *(const float2*)(nb + 2*lane);
  for (int t = 0; t < 16; ++t){
    int p = wid*16 + t;
    const float* xp = x + ((size_t)(r0 + p)*NN + c)*DIMC;
    float2 xv = *(const float2*)(xp + 2*lane);
    float s = xv.x + xv.y, sq = xv.x*xv.x + xv.y*xv.y;
    #pragma unroll
    for (int o = 32; o; o >>= 1){ s += __shfl_xor(s, o); sq += __shfl_xor(sq, o); }
    float mean = s * (1.0f/128.0f);
    float var  = sq * (1.0f/128.0f) - mean*mean;
    float inv  = rsqrtf(var + EPSV);
    u16 h0 = f2b((xv.x - mean)*inv*nw2.x + nb2.x);
    u16 h1 = f2b((xv.y - mean)*inv*nw2.y + nb2.y);
    uint32_t pk = (uint32_t)h0 | ((uint32_t)h1 << 16);
    *(uint32_t*)(xn + p*136 + 2*lane) = pk;
  }
  __syncthreads();

  const int rowA = wid*16 + (lane & 15);
  const int kofs = (lane >> 4) * 8;
  const int eoff = lane & 15;

  // pair 0: left*sigmoid(lgate) -> Lp ; pair 1: right*sigmoid(rgate) -> Rp
  for (int pr = 0; pr < 2; ++pr){
    const u16* wV = wb + (pr*2 + 0)*16384;
    const u16* wG = wb + (pr*2 + 1)*16384;
    const float* bV = pr ? right_b : left_b;
    const float* bG = pr ? rgate_b : lgate_b;
    u16* dst = pr ? Rp : Lp;
    f32x4 accV[8], accG[8];
    #pragma unroll
    for (int n = 0; n < 8; ++n){ accV[n] = {0.f,0.f,0.f,0.f}; accG[n] = {0.f,0.f,0.f,0.f}; }
    #pragma unroll
    for (int ks = 0; ks < 4; ++ks){
      bf16x8 af = *(const bf16x8*)(xn + rowA*136 + ks*32 + kofs);
      #pragma unroll
      for (int n = 0; n < 8; ++n){
        int e = n*16 + eoff;
        bf16x8 b0 = *(const bf16x8*)(wV + e*128 + ks*32 + kofs);
        bf16x8 b1 = *(const bf16x8*)(wG + e*128 + ks*32 + kofs);
        accV[n] = __builtin_amdgcn_mfma_f32_16x16x32_bf16(af, b0, accV[n], 0, 0, 0);
        accG[n] = __builtin_amdgcn_mfma_f32_16x16x32_bf16(af, b1, accG[n], 0, 0, 0);
      }
    }
    // epilogue: bias + gate, stage transposed [e][p]
    #pragma unroll
    for (int n = 0; n < 8; ++n){
      int e = n*16 + eoff;
      float bv = bV[e], bg = bG[e];
      #pragma unroll
      for (int r = 0; r < 4; ++r){
        int p = wid*16 + ((lane >> 4) << 2) + r;
        float v = (accV[n][r] + bv) * sigm(accG[n][r] + bg);
        trans[e*68 + p] = f2b(v);
      }
    }
    __syncthreads();
    // coalesced write: dst[e][c][r0..r0+63]
    for (int idx = tid; idx < 2048; idx += 256){
      int e = idx >> 4, seg = idx & 15;
      bf16x4 v = *(const bf16x4*)(trans + e*68 + seg*4);
      *(bf16x4*)(dst + (size_t)e*NPOS + (size_t)c*NN + r0 + seg*4) = v;
    }
    __syncthreads();
  }

  // ogate -> sigmoid -> gate[i][j][e]
  {
    const u16* wO = wb + 4*16384;
    f32x4 accG[8];
    #pragma unroll
    for (int n = 0; n < 8; ++n) accG[n] = {0.f,0.f,0.f,0.f};
    #pragma unroll
    for (int ks = 0; ks < 4; ++ks){
      bf16x8 af = *(const bf16x8*)(xn + rowA*136 + ks*32 + kofs);
      #pragma unroll
      for (int n = 0; n < 8; ++n){
        bf16x8 b1 = *(const bf16x8*)(wO + (n*16+eoff)*128 + ks*32 + kofs);
        accG[n] = __builtin_amdgcn_mfma_f32_16x16x32_bf16(af, b1, accG[n], 0, 0, 0);
      }
    }
    #pragma unroll
    for (int n = 0; n < 8; ++n){
      int e = n*16 + eoff;
      float bg = ogate_b[e];
      #pragma unroll
      for (int r = 0; r < 4; ++r){
        int p = wid*16 + ((lane >> 4) << 2) + r;
        trans[p*132 + e] = f2b(sigm(accG[n][r] + bg));
      }
    }
    __syncthreads();
    for (int idx = tid; idx < 2048; idx += 256){
      int p = idx >> 5, seg = idx & 31;
      bf16x4 v = *(const bf16x4*)(trans + p*132 + seg*4);
      *(bf16x4*)(gate + ((size_t)(r0 + p)*NN + c)*DIMC + seg*4) = v;
    }
  }
}

// ---------------- kernel 2: triangle einsum as 128 per-channel GEMMs ----------------
// out_pre[d][i][j] = sum_k Rp[d][i][k] * Lp[d][j][k].  Block: one d, 128x128 tile, K=384.
__global__ __launch_bounds__(256) void phase2_k(const u16* __restrict__ Rp, const u16* __restrict__ Lp,
                                                u16* __restrict__ outp){
  __shared__ u16 At[128*40];  // [row][32+8 pad]
  __shared__ u16 Bt[128*40];
  const int tid = threadIdx.x, lane = tid & 63, wid = tid >> 6;
  const int bid = blockIdx.x;
  const int d = bid / 9, tile = bid % 9;
  const int i0 = (tile/3)*128, j0 = (tile%3)*128;
  const u16* Rb = Rp + (size_t)d*NPOS;
  const u16* Lb = Lp + (size_t)d*NPOS;
  const int wm = wid >> 1, wn = wid & 1;
  const int iw = wm*64, jw = wn*64;
  const int row16 = lane & 15, kofs = (lane >> 4)*8;

  f32x4 acc[4][4];
  #pragma unroll
  for (int m = 0; m < 4; ++m)
    #pragma unroll
    for (int n = 0; n < 4; ++n) acc[m][n] = {0.f,0.f,0.f,0.f};

  for (int k0 = 0; k0 < NN; k0 += 32){
    __syncthreads();
    for (int idx = tid; idx < 512; idx += 256){
      int row = idx >> 2, seg = idx & 3;
      *(bf16x8*)(At + row*40 + seg*8) = *(const bf16x8*)(Rb + (size_t)(i0+row)*NN + k0 + seg*8);
      *(bf16x8*)(Bt + row*40 + seg*8) = *(const bf16x8*)(Lb + (size_t)(j0+row)*NN + k0 + seg*8);
    }
    __syncthreads();
    bf16x8 af[4], bfr[4];
    #pragma unroll
    for (int m = 0; m < 4; ++m) af[m]  = *(const bf16x8*)(At + (iw + m*16 + row16)*40 + kofs);
    #pragma unroll
    for (int n = 0; n < 4; ++n) bfr[n] = *(const bf16x8*)(Bt + (jw + n*16 + row16)*40 + kofs);
    #pragma unroll
    for (int m = 0; m < 4; ++m)
      #pragma unroll
      for (int n = 0; n < 4; ++n)
        acc[m][n] = __builtin_amdgcn_mfma_f32_16x16x32_bf16(af[m], bfr[n], acc[m][n], 0, 0, 0);
  }
  u16* ob = outp + (size_t)d*NPOS;
  #pragma unroll
  for (int m = 0; m < 4; ++m)
    #pragma unroll
    for (int n = 0; n < 4; ++n)
      #pragma unroll
      for (int r = 0; r < 4; ++r){
        int i = i0 + iw + m*16 + ((lane >> 4) << 2) + r;
        int j = j0 + jw + n*16 + (lane & 15);
        ob[(size_t)i*NN + j] = f2b(acc[m][n][r]);
      }
}

// ---------------- kernel 3: LN + out-projection + gate ----------------
// block: fixed i, 64 consecutive j. lane = local j; wave w holds h = w*32..w*32+31 in regs.
__global__ __launch_bounds__(256) void phase3_k(const u16* __restrict__ outp,
    const float* __restrict__ tonw, const float* __restrict__ tonb,
    const u16* __restrict__ wOut, const float* __restrict__ out_b,
    const u16* __restrict__ gate, float* __restrict__ out)
{
  __shared__ u16 xn2[64*132];       // [pos][128+4 pad]
  __shared__ float reds[4][64], redq[4][64];
  __shared__ float marr[64], iarr[64];
  const int tid = threadIdx.x, lane = tid & 63, wid = tid >> 6;
  const int bid = blockIdx.x;
  const int i = bid % NN, j0 = (bid / NN) * 64;

  float rv[32];
  float s = 0.f, sq = 0.f;
  #pragma unroll
  for (int q = 0; q < 32; ++q){
    int h = wid*32 + q;
    float v = b2f(outp[(size_t)h*NPOS + (size_t)i*NN + j0 + lane]);
    rv[q] = v; s += v; sq += v*v;
  }
  reds[wid][lane] = s; redq[wid][lane] = sq;
  __syncthreads();
  if (tid < 64){
    float ts = reds[0][tid] + reds[1][tid] + reds[2][tid] + reds[3][tid];
    float tq = redq[0][tid] + redq[1][tid] + redq[2][tid] + redq[3][tid];
    float m  = ts * (1.f/128.f);
    float var = tq * (1.f/128.f) - m*m;
    marr[tid] = m; iarr[tid] = rsqrtf(var + EPSV);
  }
  __syncthreads();
  float m = marr[lane], inv = iarr[lane];
  #pragma unroll
  for (int q = 0; q < 32; ++q){
    int h = wid*32 + q;
    float v = (rv[q] - m)*inv*tonw[h] + tonb[h];
    xn2[lane*132 + h] = f2b(v);
  }
  __syncthreads();

  f32x4 acc[8];
  #pragma unroll
  for (int n = 0; n < 8; ++n) acc[n] = {0.f,0.f,0.f,0.f};
  const int row = wid*16 + (lane & 15);
  const int kofs = (lane >> 4) * 8;
  #pragma unroll
  for (int ks = 0; ks < 4; ++ks){
    const u16* ap = xn2 + row*132 + ks*32 + kofs;
    bf16x4 a0 = *(const bf16x4*)ap;
    bf16x4 a1 = *(const bf16x4*)(ap + 4);
    bf16x8 af = __builtin_shufflevector(a0, a1, 0,1,2,3,4,5,6,7);
    #pragma unroll
    for (int n = 0; n < 8; ++n){
      bf16x8 bm = *(const bf16x8*)(wOut + (n*16 + (lane & 15))*128 + ks*32 + kofs);
      acc[n] = __builtin_amdgcn_mfma_f32_16x16x32_bf16(af, bm, acc[n], 0, 0, 0);
    }
  }
  #pragma unroll
  for (int n = 0; n < 8; ++n){
    int dd = n*16 + (lane & 15);
    float bo = out_b[dd];
    #pragma unroll
    for (int r = 0; r < 4; ++r){
      int p = wid*16 + ((lane >> 4) << 2) + r;
      size_t base = ((size_t)i*NN + j0 + p)*DIMC + dd;
      float g = b2f(gate[base]);
      out[base] = (acc[n][r] + bo) * g;
    }
  }
}

extern "C" void kernel_launch(void* const* d_in, const int* in_sizes, int n_in,
                              void* d_out, int out_size, void* d_ws, size_t ws_size,
                              hipStream_t stream){
  const float* x       = (const float*)d_in[0];
  const float* norm_w  = (const float*)d_in[1];
  const float* norm_b  = (const float*)d_in[2];
  const float* left_w  = (const float*)d_in[3];
  const float* left_b  = (const float*)d_in[4];
  const float* right_w = (const float*)d_in[5];
  const float* right_b = (const float*)d_in[6];
  const float* lgate_w = (const float*)d_in[7];
  const float* lgate_b = (const float*)d_in[8];
  const float* rgate_w = (const float*)d_in[9];
  const float* rgate_b = (const float*)d_in[10];
  const float* ogate_w = (const float*)d_in[11];
  const float* ogate_b = (const float*)d_in[12];
  const float* ton_w   = (const float*)d_in[13];
  const float* ton_b   = (const float*)d_in[14];
  const float* out_w   = (const float*)d_in[15];
  const float* out_b   = (const float*)d_in[16];

  char* ws = (char*)d_ws;
  const size_t SZ = (size_t)NPOS * DIMC * sizeof(u16);   // 37,748,736 B
  u16* Lp   = (u16*)(ws);
  u16* Rp   = (u16*)(ws + SZ);
  u16* gate = (u16*)(ws + 2*SZ);
  u16* outp = (u16*)(ws + 3*SZ);
  u16* wb   = (u16*)(ws + 4*SZ);                         // 6 * 16384 bf16

  wconv_k<<<dim3(384), dim3(256), 0, stream>>>(left_w, lgate_w, right_w, rgate_w, ogate_w, out_w, wb);
  phase1_k<<<dim3(2304), dim3(256), 0, stream>>>(x, norm_w, norm_b, wb,
      left_b, lgate_b, right_b, rgate_b, ogate_b, Lp, Rp, gate);
  phase2_k<<<dim3(1152), dim3(256), 0, stream>>>(Rp, Lp, outp);
  phase3_k<<<dim3(2304), dim3(256), 0, stream>>>(outp, ton_w, ton_b, wb + 5*16384, out_b, gate, (float*)d_out);
}

// Round 2
// 197.244 us; speedup vs baseline: 1.6359x; 1.6359x over previous
//
#include <hip/hip_runtime.h>
#include <stdint.h>

typedef unsigned short u16;
typedef short bf16x8 __attribute__((ext_vector_type(8)));
typedef short bf16x4 __attribute__((ext_vector_type(4)));
typedef float f32x4 __attribute__((ext_vector_type(4)));

#define NN 384
#define DIMC 128
#define NPOS (NN*NN)
#define EPSV 1e-5f
#define LNS 136   // xn LDS row stride in u16 (16B-aligned rows, m97-class pad)

__device__ __forceinline__ u16 f2b(float f){
  union { float f; uint32_t u; } v; v.f = f;
  return (u16)((v.u + 0x7FFFu + ((v.u >> 16) & 1u)) >> 16);
}
__device__ __forceinline__ float b2f(u16 h){
  union { uint32_t u; float f; } v; v.u = ((uint32_t)h) << 16;
  return v.f;
}
__device__ __forceinline__ float sigm(float z){ return 1.0f/(1.0f + __expf(-z)); }

// ---------------- kernel 0: fp32 -> bf16 weight conversion ----------------
// dst layout: [0]=left_w [1]=lgate_w [2]=right_w [3]=rgate_w [4]=ogate_w [5]=out_w
__global__ void wconv_k(const float* __restrict__ s0, const float* __restrict__ s1,
                        const float* __restrict__ s2, const float* __restrict__ s3,
                        const float* __restrict__ s4, const float* __restrict__ s5,
                        u16* __restrict__ dst){
  int bid = blockIdx.x;
  int m = bid >> 6;
  int off = ((bid & 63) << 8) + threadIdx.x;
  const float* src = s0;
  if (m==1) src=s1; else if (m==2) src=s2; else if (m==3) src=s3;
  else if (m==4) src=s4; else if (m==5) src=s5;
  dst[(m<<14) + off] = f2b(src[off]);
}

// ---------------- kernel 1: LN + 5 projections, single barrier ----------------
// block: fixed column c, 64 rows r0..r0+63, 256 threads (4 waves).
// wave w owns output channels e in [w*32, w*32+32), all 64 positions.
// Lp/Rp passes: mfma(A=w, B=xn) -> D[row=e][col=p] -> direct stores.
// ogate pass:   mfma(A=xn, B=w) -> D[row=p][col=e] -> direct stores.
__global__ __launch_bounds__(256) void proj_k(
    const float* __restrict__ x, const float* __restrict__ nw, const float* __restrict__ nb,
    const u16* __restrict__ wb,
    const float* __restrict__ left_b, const float* __restrict__ lgate_b,
    const float* __restrict__ right_b, const float* __restrict__ rgate_b,
    const float* __restrict__ ogate_b,
    u16* __restrict__ Lp, u16* __restrict__ Rp, u16* __restrict__ gate)
{
  __shared__ u16 xn[64*LNS];
  const int tid = threadIdx.x, lane = tid & 63, wid = tid >> 6;
  const int bid = blockIdx.x;
  const int c = bid % NN, r0 = (bid / NN) * 64;

  // ---- LN phase: 16 independent loads in flight, then reduce ----
  float2 nw2 = *(const float2*)(nw + 2*lane);
  float2 nb2 = *(const float2*)(nb + 2*lane);
  float2 xv[16];
  #pragma unroll
  for (int t = 0; t < 16; ++t){
    int p = wid*16 + t;
    xv[t] = *(const float2*)(x + ((size_t)(r0 + p)*NN + c)*DIMC + 2*lane);
  }
  #pragma unroll
  for (int t = 0; t < 16; ++t){
    int p = wid*16 + t;
    float s = xv[t].x + xv[t].y, sq = xv[t].x*xv[t].x + xv[t].y*xv[t].y;
    #pragma unroll
    for (int o = 32; o; o >>= 1){ s += __shfl_xor(s, o); sq += __shfl_xor(sq, o); }
    float mean = s * (1.0f/128.0f);
    float var  = sq * (1.0f/128.0f) - mean*mean;
    float inv  = rsqrtf(var + EPSV);
    u16 h0 = f2b((xv[t].x - mean)*inv*nw2.x + nb2.x);
    u16 h1 = f2b((xv[t].y - mean)*inv*nw2.y + nb2.y);
    uint32_t pk = (uint32_t)h0 | ((uint32_t)h1 << 16);
    *(uint32_t*)(xn + p*LNS + 2*lane) = pk;
  }
  __syncthreads();

  const int l15 = lane & 15, lg = lane >> 4;
  const int kofs = lg * 8;
  // per-lane fragment byte offsets
  const int wrow = (wid*32 + l15) * 128;     // weight row for e = wid*32 + n*16 + l15 (add n*16*128)
  const int xrowbase = l15 * LNS;            // xn row for p = pt*16 + l15 (add pt*16*LNS)

  // ---- passes 0/1: value*sigmoid(gate) -> Lp / Rp ----
  #pragma unroll
  for (int pr = 0; pr < 2; ++pr){
    const u16* wV = wb + (pr*2 + 0)*16384;
    const u16* wG = wb + (pr*2 + 1)*16384;
    const float* bV = pr ? right_b : left_b;
    const float* bG = pr ? rgate_b : lgate_b;
    u16* dst = pr ? Rp : Lp;

    f32x4 aV[2][4], aG[2][4];
    #pragma unroll
    for (int n = 0; n < 2; ++n)
      #pragma unroll
      for (int pt = 0; pt < 4; ++pt){ aV[n][pt] = {0.f,0.f,0.f,0.f}; aG[n][pt] = {0.f,0.f,0.f,0.f}; }

    #pragma unroll
    for (int ks = 0; ks < 4; ++ks){
      bf16x8 xf[4];
      #pragma unroll
      for (int pt = 0; pt < 4; ++pt)
        xf[pt] = *(const bf16x8*)(xn + xrowbase + pt*16*LNS + ks*32 + kofs);
      #pragma unroll
      for (int n = 0; n < 2; ++n){
        bf16x8 wv = *(const bf16x8*)(wV + wrow + n*16*128 + ks*32 + kofs);
        bf16x8 wg = *(const bf16x8*)(wG + wrow + n*16*128 + ks*32 + kofs);
        #pragma unroll
        for (int pt = 0; pt < 4; ++pt){
          aV[n][pt] = __builtin_amdgcn_mfma_f32_16x16x32_bf16(wv, xf[pt], aV[n][pt], 0, 0, 0);
          aG[n][pt] = __builtin_amdgcn_mfma_f32_16x16x32_bf16(wg, xf[pt], aG[n][pt], 0, 0, 0);
        }
      }
    }
    // epilogue: bias + sigmoid gate, direct stores (D row=e, col=p)
    #pragma unroll
    for (int n = 0; n < 2; ++n){
      int ebase = wid*32 + n*16 + lg*4;
      float4 bv4 = *(const float4*)(bV + ebase);
      float4 bg4 = *(const float4*)(bG + ebase);
      #pragma unroll
      for (int pt = 0; pt < 4; ++pt){
        #pragma unroll
        for (int r = 0; r < 4; ++r){
          float bv = r==0?bv4.x : r==1?bv4.y : r==2?bv4.z : bv4.w;
          float bg = r==0?bg4.x : r==1?bg4.y : r==2?bg4.z : bg4.w;
          float v = (aV[n][pt][r] + bv) * sigm(aG[n][pt][r] + bg);
          dst[(size_t)(ebase + r)*NPOS + (size_t)c*NN + (r0 + pt*16 + l15)] = f2b(v);
        }
      }
    }
  }

  // ---- pass 2: ogate -> sigmoid -> gate[i][j][e] ----
  {
    const u16* wO = wb + 4*16384;
    f32x4 aO[4][2];
    #pragma unroll
    for (int pt = 0; pt < 4; ++pt)
      #pragma unroll
      for (int n = 0; n < 2; ++n) aO[pt][n] = {0.f,0.f,0.f,0.f};

    #pragma unroll
    for (int ks = 0; ks < 4; ++ks){
      bf16x8 xf[4];
      #pragma unroll
      for (int pt = 0; pt < 4; ++pt)
        xf[pt] = *(const bf16x8*)(xn + xrowbase + pt*16*LNS + ks*32 + kofs);
      #pragma unroll
      for (int n = 0; n < 2; ++n){
        bf16x8 wo = *(const bf16x8*)(wO + wrow + n*16*128 + ks*32 + kofs);
        #pragma unroll
        for (int pt = 0; pt < 4; ++pt)
          aO[pt][n] = __builtin_amdgcn_mfma_f32_16x16x32_bf16(xf[pt], wo, aO[pt][n], 0, 0, 0);
      }
    }
    float bo0 = ogate_b[wid*32 + l15];
    float bo1 = ogate_b[wid*32 + 16 + l15];
    #pragma unroll
    for (int pt = 0; pt < 4; ++pt){
      #pragma unroll
      for (int n = 0; n < 2; ++n){
        int e = wid*32 + n*16 + l15;
        float bo = n ? bo1 : bo0;
        #pragma unroll
        for (int r = 0; r < 4; ++r){
          int p = pt*16 + lg*4 + r;
          gate[((size_t)(r0 + p)*NN + c)*DIMC + e] = f2b(sigm(aO[pt][n][r] + bo));
        }
      }
    }
  }
}

// ---------------- kernel 2: triangle einsum as 128 per-channel GEMMs ----------------
// out_pre[d][i][j] = sum_k Rp[d][i][k] * Lp[d][j][k].  Block: one d, 128x128 tile, K=384.
__global__ __launch_bounds__(256) void phase2_k(const u16* __restrict__ Rp, const u16* __restrict__ Lp,
                                                u16* __restrict__ outp){
  __shared__ u16 At[128*40];  // [row][32+8 pad]
  __shared__ u16 Bt[128*40];
  const int tid = threadIdx.x, lane = tid & 63, wid = tid >> 6;
  const int bid = blockIdx.x;
  const int d = bid / 9, tile = bid % 9;
  const int i0 = (tile/3)*128, j0 = (tile%3)*128;
  const u16* Rb = Rp + (size_t)d*NPOS;
  const u16* Lb = Lp + (size_t)d*NPOS;
  const int wm = wid >> 1, wn = wid & 1;
  const int iw = wm*64, jw = wn*64;
  const int row16 = lane & 15, kofs = (lane >> 4)*8;

  f32x4 acc[4][4];
  #pragma unroll
  for (int m = 0; m < 4; ++m)
    #pragma unroll
    for (int n = 0; n < 4; ++n) acc[m][n] = {0.f,0.f,0.f,0.f};

  for (int k0 = 0; k0 < NN; k0 += 32){
    __syncthreads();
    for (int idx = tid; idx < 512; idx += 256){
      int row = idx >> 2, seg = idx & 3;
      *(bf16x8*)(At + row*40 + seg*8) = *(const bf16x8*)(Rb + (size_t)(i0+row)*NN + k0 + seg*8);
      *(bf16x8*)(Bt + row*40 + seg*8) = *(const bf16x8*)(Lb + (size_t)(j0+row)*NN + k0 + seg*8);
    }
    __syncthreads();
    bf16x8 af[4], bfr[4];
    #pragma unroll
    for (int m = 0; m < 4; ++m) af[m]  = *(const bf16x8*)(At + (iw + m*16 + row16)*40 + kofs);
    #pragma unroll
    for (int n = 0; n < 4; ++n) bfr[n] = *(const bf16x8*)(Bt + (jw + n*16 + row16)*40 + kofs);
    #pragma unroll
    for (int m = 0; m < 4; ++m)
      #pragma unroll
      for (int n = 0; n < 4; ++n)
        acc[m][n] = __builtin_amdgcn_mfma_f32_16x16x32_bf16(af[m], bfr[n], acc[m][n], 0, 0, 0);
  }
  u16* ob = outp + (size_t)d*NPOS;
  #pragma unroll
  for (int m = 0; m < 4; ++m)
    #pragma unroll
    for (int n = 0; n < 4; ++n)
      #pragma unroll
      for (int r = 0; r < 4; ++r){
        int i = i0 + iw + m*16 + ((lane >> 4) << 2) + r;
        int j = j0 + jw + n*16 + (lane & 15);
        ob[(size_t)i*NN + j] = f2b(acc[m][n][r]);
      }
}

// ---------------- kernel 3: LN + out-projection + gate ----------------
__global__ __launch_bounds__(256) void phase3_k(const u16* __restrict__ outp,
    const float* __restrict__ tonw, const float* __restrict__ tonb,
    const u16* __restrict__ wOut, const float* __restrict__ out_b,
    const u16* __restrict__ gate, float* __restrict__ out)
{
  __shared__ u16 xn2[64*132];
  __shared__ float reds[4][64], redq[4][64];
  __shared__ float marr[64], iarr[64];
  const int tid = threadIdx.x, lane = tid & 63, wid = tid >> 6;
  const int bid = blockIdx.x;
  const int i = bid % NN, j0 = (bid / NN) * 64;

  float rv[32];
  float s = 0.f, sq = 0.f;
  #pragma unroll
  for (int q = 0; q < 32; ++q){
    int h = wid*32 + q;
    float v = b2f(outp[(size_t)h*NPOS + (size_t)i*NN + j0 + lane]);
    rv[q] = v; s += v; sq += v*v;
  }
  reds[wid][lane] = s; redq[wid][lane] = sq;
  __syncthreads();
  if (tid < 64){
    float ts = reds[0][tid] + reds[1][tid] + reds[2][tid] + reds[3][tid];
    float tq = redq[0][tid] + redq[1][tid] + redq[2][tid] + redq[3][tid];
    float m  = ts * (1.f/128.f);
    float var = tq * (1.f/128.f) - m*m;
    marr[tid] = m; iarr[tid] = rsqrtf(var + EPSV);
  }
  __syncthreads();
  float m = marr[lane], inv = iarr[lane];
  #pragma unroll
  for (int q = 0; q < 32; ++q){
    int h = wid*32 + q;
    float v = (rv[q] - m)*inv*tonw[h] + tonb[h];
    xn2[lane*132 + h] = f2b(v);
  }
  __syncthreads();

  f32x4 acc[8];
  #pragma unroll
  for (int n = 0; n < 8; ++n) acc[n] = {0.f,0.f,0.f,0.f};
  const int row = wid*16 + (lane & 15);
  const int kofs = (lane >> 4) * 8;
  #pragma unroll
  for (int ks = 0; ks < 4; ++ks){
    const u16* ap = xn2 + row*132 + ks*32 + kofs;
    bf16x4 a0 = *(const bf16x4*)ap;
    bf16x4 a1 = *(const bf16x4*)(ap + 4);
    bf16x8 af = __builtin_shufflevector(a0, a1, 0,1,2,3,4,5,6,7);
    #pragma unroll
    for (int n = 0; n < 8; ++n){
      bf16x8 bm = *(const bf16x8*)(wOut + (n*16 + (lane & 15))*128 + ks*32 + kofs);
      acc[n] = __builtin_amdgcn_mfma_f32_16x16x32_bf16(af, bm, acc[n], 0, 0, 0);
    }
  }
  #pragma unroll
  for (int n = 0; n < 8; ++n){
    int dd = n*16 + (lane & 15);
    float bo = out_b[dd];
    #pragma unroll
    for (int r = 0; r < 4; ++r){
      int p = wid*16 + ((lane >> 4) << 2) + r;
      size_t base = ((size_t)i*NN + j0 + p)*DIMC + dd;
      float g = b2f(gate[base]);
      out[base] = (acc[n][r] + bo) * g;
    }
  }
}

extern "C" void kernel_launch(void* const* d_in, const int* in_sizes, int n_in,
                              void* d_out, int out_size, void* d_ws, size_t ws_size,
                              hipStream_t stream){
  const float* x       = (const float*)d_in[0];
  const float* norm_w  = (const float*)d_in[1];
  const float* norm_b  = (const float*)d_in[2];
  const float* left_w  = (const float*)d_in[3];
  const float* left_b  = (const float*)d_in[4];
  const float* right_w = (const float*)d_in[5];
  const float* right_b = (const float*)d_in[6];
  const float* lgate_w = (const float*)d_in[7];
  const float* lgate_b = (const float*)d_in[8];
  const float* rgate_w = (const float*)d_in[9];
  const float* rgate_b = (const float*)d_in[10];
  const float* ogate_w = (const float*)d_in[11];
  const float* ogate_b = (const float*)d_in[12];
  const float* ton_w   = (const float*)d_in[13];
  const float* ton_b   = (const float*)d_in[14];
  const float* out_w   = (const float*)d_in[15];
  const float* out_b   = (const float*)d_in[16];

  char* ws = (char*)d_ws;
  const size_t SZ = (size_t)NPOS * DIMC * sizeof(u16);
  u16* Lp   = (u16*)(ws);
  u16* Rp   = (u16*)(ws + SZ);
  u16* gate = (u16*)(ws + 2*SZ);
  u16* outp = (u16*)(ws + 3*SZ);
  u16* wb   = (u16*)(ws + 4*SZ);

  wconv_k<<<dim3(384), dim3(256), 0, stream>>>(left_w, lgate_w, right_w, rgate_w, ogate_w, out_w, wb);
  proj_k<<<dim3(2304), dim3(256), 0, stream>>>(x, norm_w, norm_b, wb,
      left_b, lgate_b, right_b, rgate_b, ogate_b, Lp, Rp, gate);
  phase2_k<<<dim3(1152), dim3(256), 0, stream>>>(Rp, Lp, outp);
  phase3_k<<<dim3(2304), dim3(256), 0, stream>>>(outp, ton_w, ton_b, wb + 5*16384, out_b, gate, (float*)d_out);
}

// Round 3
// 194.656 us; speedup vs baseline: 1.6576x; 1.0133x over previous
//
#include <hip/hip_runtime.h>
#include <stdint.h>

typedef unsigned short u16;
typedef short bf16x8 __attribute__((ext_vector_type(8)));
typedef short bf16x4 __attribute__((ext_vector_type(4)));
typedef float f32x4 __attribute__((ext_vector_type(4)));

#define NN 384
#define DIMC 128
#define NPOS (NN*NN)
#define EPSV 1e-5f
#define LNS 136   // xn LDS row stride in u16

__device__ __forceinline__ u16 f2b(float f){
  union { float f; uint32_t u; } v; v.f = f;
  return (u16)((v.u + 0x7FFFu + ((v.u >> 16) & 1u)) >> 16);
}
__device__ __forceinline__ float b2f(u16 h){
  union { uint32_t u; float f; } v; v.u = ((uint32_t)h) << 16;
  return v.f;
}
__device__ __forceinline__ float sigm(float z){ return 1.0f/(1.0f + __expf(-z)); }

__device__ __forceinline__ void glds16(const u16* g, u16* l){
  __builtin_amdgcn_global_load_lds((const __attribute__((address_space(1))) void*)(g),
                                   (__attribute__((address_space(3))) void*)(l), 16, 0, 0);
}

// ---------------- kernel 0: fp32 -> bf16 weight conversion ----------------
__global__ void wconv_k(const float* __restrict__ s0, const float* __restrict__ s1,
                        const float* __restrict__ s2, const float* __restrict__ s3,
                        const float* __restrict__ s4, const float* __restrict__ s5,
                        u16* __restrict__ dst){
  int bid = blockIdx.x;
  int m = bid >> 6;
  int off = ((bid & 63) << 8) + threadIdx.x;
  const float* src = s0;
  if (m==1) src=s1; else if (m==2) src=s2; else if (m==3) src=s3;
  else if (m==4) src=s4; else if (m==5) src=s5;
  dst[(m<<14) + off] = f2b(src[off]);
}

// ---------------- kernel 1: LN + 5 projections ----------------
// block: fixed column c, 64 rows r0..r0+63, 256 threads (4 waves).
// L/R: mfma(A=w, B=xn) -> D[e][p]; stage LDS [e][72] -> b128 stores.
// O:   mfma(A=xn, B=w) -> D[p][e]; stage LDS [p][136] -> b128 stores.
__global__ __launch_bounds__(256) void proj_k(
    const float* __restrict__ x, const float* __restrict__ nw, const float* __restrict__ nb,
    const u16* __restrict__ wb,
    const float* __restrict__ left_b, const float* __restrict__ lgate_b,
    const float* __restrict__ right_b, const float* __restrict__ rgate_b,
    const float* __restrict__ ogate_b,
    u16* __restrict__ Lp, u16* __restrict__ Rp, u16* __restrict__ gate)
{
  __shared__ u16 xn[64*LNS];     // 17408 B
  __shared__ u16 trans[9216];    // 18432 B staging (L/R: [128][72]; O: [64][136])
  const int tid = threadIdx.x, lane = tid & 63, wid = tid >> 6;
  const int bid = blockIdx.x;
  const int c = bid % NN, r0 = (bid / NN) * 64;

  // ---- LN: 16 independent loads in flight per wave ----
  float2 nw2 = *(const float2*)(nw + 2*lane);
  float2 nb2 = *(const float2*)(nb + 2*lane);
  float2 xv[16];
  #pragma unroll
  for (int t = 0; t < 16; ++t){
    int p = wid*16 + t;
    xv[t] = *(const float2*)(x + ((size_t)(r0 + p)*NN + c)*DIMC + 2*lane);
  }
  #pragma unroll
  for (int t = 0; t < 16; ++t){
    int p = wid*16 + t;
    float s = xv[t].x + xv[t].y, sq = xv[t].x*xv[t].x + xv[t].y*xv[t].y;
    #pragma unroll
    for (int o = 32; o; o >>= 1){ s += __shfl_xor(s, o); sq += __shfl_xor(sq, o); }
    float mean = s * (1.0f/128.0f);
    float var  = sq * (1.0f/128.0f) - mean*mean;
    float inv  = rsqrtf(var + EPSV);
    u16 h0 = f2b((xv[t].x - mean)*inv*nw2.x + nb2.x);
    u16 h1 = f2b((xv[t].y - mean)*inv*nw2.y + nb2.y);
    uint32_t pk = (uint32_t)h0 | ((uint32_t)h1 << 16);
    *(uint32_t*)(xn + p*LNS + 2*lane) = pk;
  }
  __syncthreads();

  const int l15 = lane & 15, lg = lane >> 4;
  const int kofs = lg * 8;
  const int wrow = (wid*32 + l15) * 128;
  const int xrowbase = l15 * LNS;

  // ---- passes 0/1: value*sigmoid(gate) -> Lp / Rp ----
  #pragma unroll
  for (int pr = 0; pr < 2; ++pr){
    const u16* wV = wb + (pr*2 + 0)*16384;
    const u16* wG = wb + (pr*2 + 1)*16384;
    const float* bV = pr ? right_b : left_b;
    const float* bG = pr ? rgate_b : lgate_b;
    u16* dst = pr ? Rp : Lp;

    f32x4 aV[2][4], aG[2][4];
    #pragma unroll
    for (int n = 0; n < 2; ++n)
      #pragma unroll
      for (int pt = 0; pt < 4; ++pt){ aV[n][pt] = {0.f,0.f,0.f,0.f}; aG[n][pt] = {0.f,0.f,0.f,0.f}; }

    #pragma unroll
    for (int ks = 0; ks < 4; ++ks){
      bf16x8 xf[4];
      #pragma unroll
      for (int pt = 0; pt < 4; ++pt)
        xf[pt] = *(const bf16x8*)(xn + xrowbase + pt*16*LNS + ks*32 + kofs);
      #pragma unroll
      for (int n = 0; n < 2; ++n){
        bf16x8 wv = *(const bf16x8*)(wV + wrow + n*16*128 + ks*32 + kofs);
        bf16x8 wg = *(const bf16x8*)(wG + wrow + n*16*128 + ks*32 + kofs);
        #pragma unroll
        for (int pt = 0; pt < 4; ++pt){
          aV[n][pt] = __builtin_amdgcn_mfma_f32_16x16x32_bf16(wv, xf[pt], aV[n][pt], 0, 0, 0);
          aG[n][pt] = __builtin_amdgcn_mfma_f32_16x16x32_bf16(wg, xf[pt], aG[n][pt], 0, 0, 0);
        }
      }
    }
    // stage [e][72]
    #pragma unroll
    for (int n = 0; n < 2; ++n){
      int ebase = wid*32 + n*16 + lg*4;
      float4 bv4 = *(const float4*)(bV + ebase);
      float4 bg4 = *(const float4*)(bG + ebase);
      #pragma unroll
      for (int pt = 0; pt < 4; ++pt){
        #pragma unroll
        for (int r = 0; r < 4; ++r){
          float bv = r==0?bv4.x : r==1?bv4.y : r==2?bv4.z : bv4.w;
          float bg = r==0?bg4.x : r==1?bg4.y : r==2?bg4.z : bg4.w;
          float v = (aV[n][pt][r] + bv) * sigm(aG[n][pt][r] + bg);
          trans[(ebase + r)*72 + pt*16 + l15] = f2b(v);
        }
      }
    }
    __syncthreads();
    // coalesced b128 stores: dst[e][c][r0 + s*8 ..]
    #pragma unroll
    for (int it = 0; it < 4; ++it){
      int idx = tid + it*256;
      int e = idx >> 3, s = idx & 7;
      *(bf16x8*)(dst + (size_t)e*NPOS + (size_t)c*NN + r0 + s*8) = *(const bf16x8*)(trans + e*72 + s*8);
    }
    __syncthreads();
  }

  // ---- pass 2: ogate -> sigmoid -> gate[i][j][e] ----
  {
    const u16* wO = wb + 4*16384;
    f32x4 aO[4][2];
    #pragma unroll
    for (int pt = 0; pt < 4; ++pt)
      #pragma unroll
      for (int n = 0; n < 2; ++n) aO[pt][n] = {0.f,0.f,0.f,0.f};

    #pragma unroll
    for (int ks = 0; ks < 4; ++ks){
      bf16x8 xf[4];
      #pragma unroll
      for (int pt = 0; pt < 4; ++pt)
        xf[pt] = *(const bf16x8*)(xn + xrowbase + pt*16*LNS + ks*32 + kofs);
      #pragma unroll
      for (int n = 0; n < 2; ++n){
        bf16x8 wo = *(const bf16x8*)(wO + wrow + n*16*128 + ks*32 + kofs);
        #pragma unroll
        for (int pt = 0; pt < 4; ++pt)
          aO[pt][n] = __builtin_amdgcn_mfma_f32_16x16x32_bf16(xf[pt], wo, aO[pt][n], 0, 0, 0);
      }
    }
    float bo0 = ogate_b[wid*32 + l15];
    float bo1 = ogate_b[wid*32 + 16 + l15];
    #pragma unroll
    for (int pt = 0; pt < 4; ++pt){
      #pragma unroll
      for (int n = 0; n < 2; ++n){
        int e = wid*32 + n*16 + l15;
        float bo = n ? bo1 : bo0;
        #pragma unroll
        for (int r = 0; r < 4; ++r){
          int p = pt*16 + lg*4 + r;
          trans[p*136 + e] = f2b(sigm(aO[pt][n][r] + bo));
        }
      }
    }
    __syncthreads();
    #pragma unroll
    for (int it = 0; it < 4; ++it){
      int idx = tid + it*256;
      int p = idx >> 4, s = idx & 15;
      *(bf16x8*)(gate + ((size_t)(r0 + p)*NN + c)*DIMC + s*8) = *(const bf16x8*)(trans + p*136 + s*8);
    }
  }
}

// ---------------- kernel 2: triangle einsum, BK=64, global_load_lds + XOR swizzle ----------------
// out_pre[d][i][j] = sum_k Rp[d][i][k] * Lp[d][j][k].  Block: one d, 128x128 tile, K=384.
// LDS linear [row][8 slots of 16B]; content at (row, slot) = global (row, slot^(row&7)).
__global__ __launch_bounds__(256) void phase2_k(const u16* __restrict__ Rp, const u16* __restrict__ Lp,
                                                u16* __restrict__ outp){
  __shared__ u16 lds[17408];          // 34816 B: K-loop A[0,8192) B[8192,16384) u16; epilogue [128][136]
  u16* At = lds;
  u16* Bt = lds + 8192;
  const int tid = threadIdx.x, lane = tid & 63, wid = tid >> 6;
  const int bid = blockIdx.x;
  const int d = bid / 9, tile = bid % 9;
  const int i0 = (tile/3)*128, j0 = (tile%3)*128;
  const u16* Rb = Rp + (size_t)d*NPOS;
  const u16* Lb = Lp + (size_t)d*NPOS;
  const int wm = wid >> 1, wn = wid & 1;
  const int iw = wm*64, jw = wn*64;
  const int l15 = lane & 15, lg = lane >> 4;
  const int rmask = l15 & 7;

  // staging geometry: per call c, linear 16B idx = wid*256 + c*64 + lane
  int srcoff[4];
  #pragma unroll
  for (int c = 0; c < 4; ++c){
    int idx = wid*256 + c*64 + lane;
    int row = idx >> 3, slot = idx & 7;
    srcoff[c] = row*NN + ((slot ^ (row & 7)) * 8);
  }

  f32x4 acc[4][4];
  #pragma unroll
  for (int m = 0; m < 4; ++m)
    #pragma unroll
    for (int n = 0; n < 4; ++n) acc[m][n] = {0.f,0.f,0.f,0.f};

  const u16* Rt0 = Rb + (size_t)i0*NN;
  const u16* Lt0 = Lb + (size_t)j0*NN;

  for (int k0 = 0; k0 < NN; k0 += 64){
    __syncthreads();
    #pragma unroll
    for (int c = 0; c < 4; ++c){
      glds16(Rt0 + k0 + srcoff[c], At + (wid*4 + c)*512);
      glds16(Lt0 + k0 + srcoff[c], Bt + (wid*4 + c)*512);
    }
    asm volatile("s_waitcnt vmcnt(0)" ::: "memory");
    __syncthreads();
    #pragma unroll
    for (int ks = 0; ks < 2; ++ks){
      int sl = ((ks*4 + lg) ^ rmask) * 8;
      bf16x8 af[4], bfr[4];
      #pragma unroll
      for (int m = 0; m < 4; ++m)
        af[m] = *(const bf16x8*)(At + (iw + m*16 + l15)*64 + sl);
      #pragma unroll
      for (int n = 0; n < 4; ++n)
        bfr[n] = *(const bf16x8*)(Bt + (jw + n*16 + l15)*64 + sl);
      #pragma unroll
      for (int m = 0; m < 4; ++m)
        #pragma unroll
        for (int n = 0; n < 4; ++n)
          acc[m][n] = __builtin_amdgcn_mfma_f32_16x16x32_bf16(af[m], bfr[n], acc[m][n], 0, 0, 0);
    }
  }

  // epilogue: stage [128][136], then 256B-run b128 stores
  __syncthreads();
  #pragma unroll
  for (int m = 0; m < 4; ++m)
    #pragma unroll
    for (int n = 0; n < 4; ++n)
      #pragma unroll
      for (int r = 0; r < 4; ++r)
        lds[(iw + m*16 + lg*4 + r)*136 + jw + n*16 + l15] = f2b(acc[m][n][r]);
  __syncthreads();
  u16* ob = outp + (size_t)d*NPOS;
  #pragma unroll
  for (int it = 0; it < 8; ++it){
    int idx = tid + it*256;
    int i = idx >> 4, s = idx & 15;
    *(bf16x8*)(ob + (size_t)(i0 + i)*NN + j0 + s*8) = *(const bf16x8*)(lds + i*136 + s*8);
  }
}

// ---------------- kernel 3: LN + out-projection + gate ----------------
__global__ __launch_bounds__(256) void phase3_k(const u16* __restrict__ outp,
    const float* __restrict__ tonw, const float* __restrict__ tonb,
    const u16* __restrict__ wOut, const float* __restrict__ out_b,
    const u16* __restrict__ gate, float* __restrict__ out)
{
  __shared__ u16 xn2[64*132];
  __shared__ float reds[4][64], redq[4][64];
  __shared__ float marr[64], iarr[64];
  const int tid = threadIdx.x, lane = tid & 63, wid = tid >> 6;
  const int bid = blockIdx.x;
  const int i = bid % NN, j0 = (bid / NN) * 64;

  float rv[32];
  float s = 0.f, sq = 0.f;
  #pragma unroll
  for (int q = 0; q < 32; ++q){
    int h = wid*32 + q;
    float v = b2f(outp[(size_t)h*NPOS + (size_t)i*NN + j0 + lane]);
    rv[q] = v; s += v; sq += v*v;
  }
  reds[wid][lane] = s; redq[wid][lane] = sq;
  __syncthreads();
  if (tid < 64){
    float ts = reds[0][tid] + reds[1][tid] + reds[2][tid] + reds[3][tid];
    float tq = redq[0][tid] + redq[1][tid] + redq[2][tid] + redq[3][tid];
    float m  = ts * (1.f/128.f);
    float var = tq * (1.f/128.f) - m*m;
    marr[tid] = m; iarr[tid] = rsqrtf(var + EPSV);
  }
  __syncthreads();
  float m = marr[lane], inv = iarr[lane];
  #pragma unroll
  for (int q = 0; q < 32; ++q){
    int h = wid*32 + q;
    float v = (rv[q] - m)*inv*tonw[h] + tonb[h];
    xn2[lane*132 + h] = f2b(v);
  }
  __syncthreads();

  f32x4 acc[8];
  #pragma unroll
  for (int n = 0; n < 8; ++n) acc[n] = {0.f,0.f,0.f,0.f};
  const int row = wid*16 + (lane & 15);
  const int kofs = (lane >> 4) * 8;
  #pragma unroll
  for (int ks = 0; ks < 4; ++ks){
    const u16* ap = xn2 + row*132 + ks*32 + kofs;
    bf16x4 a0 = *(const bf16x4*)ap;
    bf16x4 a1 = *(const bf16x4*)(ap + 4);
    bf16x8 af = __builtin_shufflevector(a0, a1, 0,1,2,3,4,5,6,7);
    #pragma unroll
    for (int n = 0; n < 8; ++n){
      bf16x8 bm = *(const bf16x8*)(wOut + (n*16 + (lane & 15))*128 + ks*32 + kofs);
      acc[n] = __builtin_amdgcn_mfma_f32_16x16x32_bf16(af, bm, acc[n], 0, 0, 0);
    }
  }
  #pragma unroll
  for (int n = 0; n < 8; ++n){
    int dd = n*16 + (lane & 15);
    float bo = out_b[dd];
    #pragma unroll
    for (int r = 0; r < 4; ++r){
      int p = wid*16 + ((lane >> 4) << 2) + r;
      size_t base = ((size_t)i*NN + j0 + p)*DIMC + dd;
      float g = b2f(gate[base]);
      out[base] = (acc[n][r] + bo) * g;
    }
  }
}

extern "C" void kernel_launch(void* const* d_in, const int* in_sizes, int n_in,
                              void* d_out, int out_size, void* d_ws, size_t ws_size,
                              hipStream_t stream){
  const float* x       = (const float*)d_in[0];
  const float* norm_w  = (const float*)d_in[1];
  const float* norm_b  = (const float*)d_in[2];
  const float* left_w  = (const float*)d_in[3];
  const float* left_b  = (const float*)d_in[4];
  const float* right_w = (const float*)d_in[5];
  const float* right_b = (const float*)d_in[6];
  const float* lgate_w = (const float*)d_in[7];
  const float* lgate_b = (const float*)d_in[8];
  const float* rgate_w = (const float*)d_in[9];
  const float* rgate_b = (const float*)d_in[10];
  const float* ogate_w = (const float*)d_in[11];
  const float* ogate_b = (const float*)d_in[12];
  const float* ton_w   = (const float*)d_in[13];
  const float* ton_b   = (const float*)d_in[14];
  const float* out_w   = (const float*)d_in[15];
  const float* out_b   = (const float*)d_in[16];

  char* ws = (char*)d_ws;
  const size_t SZ = (size_t)NPOS * DIMC * sizeof(u16);
  u16* Lp   = (u16*)(ws);
  u16* Rp   = (u16*)(ws + SZ);
  u16* gate = (u16*)(ws + 2*SZ);
  u16* outp = (u16*)(ws + 3*SZ);
  u16* wb   = (u16*)(ws + 4*SZ);

  wconv_k<<<dim3(384), dim3(256), 0, stream>>>(left_w, lgate_w, right_w, rgate_w, ogate_w, out_w, wb);
  proj_k<<<dim3(2304), dim3(256), 0, stream>>>(x, norm_w, norm_b, wb,
      left_b, lgate_b, right_b, rgate_b, ogate_b, Lp, Rp, gate);
  phase2_k<<<dim3(1152), dim3(256), 0, stream>>>(Rp, Lp, outp);
  phase3_k<<<dim3(2304), dim3(256), 0, stream>>>(outp, ton_w, ton_b, wb + 5*16384, out_b, gate, (float*)d_out);
}